// Round 16
// baseline (391.747 us; speedup 1.0000x reference)
//
#include <hip/hip_runtime.h>

// B=8, S=4096, E=256, H=4, DK=64. Tokens = B*S = 32768.
// Round-16: ABLATION v2 (NREP rebalanced; R9's flaw: only v4 cleared the
// ~44us top-5 threshold -> v1-v3 gave upper bounds only, and the "output
// path >= 27us" read-through led to a falsified epilogue fix (R15: coalesced
// epilogue changed nothing; WRITE was always payload-exact).
// Probes (per-rep = dur/NREP), all on the R8/R15 block structure:
//   p1: stage only                       NREP=20
//   p2: stage + QKV-noW (MFMA, no Wload) NREP=8   <- isolates W-load cost
//   p3: stage + QKV real                 NREP=6
//   p4: stage + QKV + softmax/ymix       NREP=4
//   fused: R15-measured kernel, unchanged, launched first.
// acc-laundering (zregf) prevents CSE of identical MFMA chains in p2;
// zreg() launder defeats LICM; asm sinks defeat DCE. dur_us sacrificed.

typedef __bf16 bf16x8 __attribute__((ext_vector_type(8)));
typedef __bf16 bf16x4 __attribute__((ext_vector_type(4)));
typedef float f32x4 __attribute__((ext_vector_type(4)));

#define LDW 264
#define MROWS 32
#define XSW(row, col) ((col) ^ ((((row) >> 3) & 1) << 4))
#define CELEM (512 * 512)
#define OSTR 260

__global__ void pack_wfrag8(const float* __restrict__ Wq, const float* __restrict__ Wk,
                            const float* __restrict__ Wv, const float* __restrict__ Wo,
                            __bf16* __restrict__ Wpk) {
  const int c = blockIdx.x & 7;
  const int f = blockIdx.x >> 3;
  const int lane = threadIdx.x;
  const int kk = f & 7, g16 = (f >> 3) & 15, p = f >> 7;
  const float* W = (p == 0) ? Wq : (p == 1) ? Wk : (p == 2) ? Wv : Wo;
  const int lh = lane & 15, lq = lane >> 4;
  const int n = g16 * 16 + lh, k0 = kk * 32 + lq * 8;
  const float4 s0 = *(const float4*)&W[n * 256 + k0];
  const float4 s1 = *(const float4*)&W[n * 256 + k0 + 4];
  bf16x8 r;
  r[0] = (__bf16)s0.x; r[1] = (__bf16)s0.y; r[2] = (__bf16)s0.z; r[3] = (__bf16)s0.w;
  r[4] = (__bf16)s1.x; r[5] = (__bf16)s1.y; r[6] = (__bf16)s1.z; r[7] = (__bf16)s1.w;
  *(bf16x8*)&Wpk[(size_t)c * CELEM + (size_t)f * 512 + lane * 8] = r;
}

__device__ __forceinline__ int zreg() { int z = 0; asm volatile("" : "+v"(z)); return z; }
__device__ __forceinline__ float zregf() { float z = 0.f; asm volatile("" : "+v"(z)); return z; }

#define MFMA(d, a, b) d = __builtin_amdgcn_mfma_f32_16x16x32_bf16(a, b, d, 0, 0, 0)

#define ZERO_ACC22(acc)                                          \
  _Pragma("unroll")                                              \
  for (int mf_ = 0; mf_ < 2; ++mf_)                              \
    _Pragma("unroll")                                            \
    for (int nf_ = 0; nf_ < 2; ++nf_)                            \
      acc[mf_][nf_] = (f32x4){0.f, 0.f, 0.f, 0.f};

__device__ __forceinline__ void stage_x(const float* __restrict__ x, __bf16* xs,
                                        int tid, int tok0, int zoff) {
  const float4* xg = (const float4*)(x + (size_t)tok0 * 256);
  #pragma unroll
  for (int i = 0; i < 4; ++i) {
    int idx = i * 512 + tid + zoff;
    int row = idx >> 6;
    int c4  = idx & 63;
    float4 v = xg[idx];
    bf16x4 pk;
    pk[0] = (__bf16)v.x; pk[1] = (__bf16)v.y; pk[2] = (__bf16)v.z; pk[3] = (__bf16)v.w;
    *(bf16x4*)&xs[row * LDW + XSW(row, c4 * 4)] = pk;
  }
}

__device__ __forceinline__ void store_cd32(__bf16* __restrict__ buf, const f32x4 acc[2][2],
                                           const float* __restrict__ bias,
                                           int n0, int lh, int lq) {
  #pragma unroll
  for (int nf = 0; nf < 2; ++nf) {
    int col = n0 + nf * 16 + lh;
    float bb = bias[col];
    #pragma unroll
    for (int mf = 0; mf < 2; ++mf) {
      int r = mf * 16 + lq * 4;
      #pragma unroll
      for (int j = 0; j < 4; ++j)
        buf[(r + j) * LDW + XSW(r + j, col)] = (__bf16)(acc[mf][nf][j] + bb);
    }
  }
}

__device__ __forceinline__ void qkv_pass(const __bf16* __restrict__ xs, __bf16* qs,
                                         __bf16* ksh, __bf16* vs,
                                         const __bf16* wlq, const __bf16* wlk,
                                         const __bf16* wlv,
                                         const float* bq, const float* bk, const float* bv,
                                         int n0, int lh, int lq) {
  f32x4 aq[2][2], ak[2][2], av[2][2];
  ZERO_ACC22(aq);
  ZERO_ACC22(ak);
  ZERO_ACC22(av);
  const int xsw = ((lh >> 3) & 1) << 4;
  const __bf16* ap = xs + lh * LDW;
  #pragma unroll
  for (int kk = 0; kk < 8; ++kk) {
    bf16x8 wq0 = *(const bf16x8*)(wlq + (0 * 8 + kk) * 512);
    bf16x8 wq1 = *(const bf16x8*)(wlq + (1 * 8 + kk) * 512);
    bf16x8 wk0 = *(const bf16x8*)(wlk + (0 * 8 + kk) * 512);
    bf16x8 wk1 = *(const bf16x8*)(wlk + (1 * 8 + kk) * 512);
    bf16x8 wv0 = *(const bf16x8*)(wlv + (0 * 8 + kk) * 512);
    bf16x8 wv1 = *(const bf16x8*)(wlv + (1 * 8 + kk) * 512);
    const int c = (kk * 32 + lq * 8) ^ xsw;
    bf16x8 a0 = *(const bf16x8*)(ap +  0 * LDW + c);
    bf16x8 a1 = *(const bf16x8*)(ap + 16 * LDW + c);
    MFMA(aq[0][0], a0, wq0); MFMA(aq[1][0], a1, wq0);
    MFMA(aq[0][1], a0, wq1); MFMA(aq[1][1], a1, wq1);
    MFMA(ak[0][0], a0, wk0); MFMA(ak[1][0], a1, wk0);
    MFMA(ak[0][1], a0, wk1); MFMA(ak[1][1], a1, wk1);
    MFMA(av[0][0], a0, wv0); MFMA(av[1][0], a1, wv0);
    MFMA(av[0][1], a0, wv1); MFMA(av[1][1], a1, wv1);
  }
  store_cd32(qs, aq, bq, n0, lh, lq);
  store_cd32(ksh, ak, bk, n0, lh, lq);
  store_cd32(vs, av, bv, n0, lh, lq);
}

__device__ __forceinline__ void sm_ymix(const __bf16* qs, const __bf16* ksh,
                                        const __bf16* vs, __bf16* ys, int tid) {
  const int lane = tid & 63;
  const int m   = tid >> 4;
  const int sub = tid & 15;
  const int h   = sub & 3;
  const int kh  = sub >> 2;
  const int dof = kh * 16;
  const int msw = ((m >> 3) & 1) << 4;
  float d0 = 0.f, d1 = 0.f, d2 = 0.f, d3 = 0.f;
  #pragma unroll
  for (int i = 0; i < 2; ++i) {
    bf16x8 qv = *(const bf16x8*)&qs[m * LDW + ((h * 64 + dof + i * 8) ^ msw)];
    bf16x8 k0 = *(const bf16x8*)&ksh[m * LDW + ((  0 + dof + i * 8) ^ msw)];
    bf16x8 k1 = *(const bf16x8*)&ksh[m * LDW + (( 64 + dof + i * 8) ^ msw)];
    bf16x8 k2 = *(const bf16x8*)&ksh[m * LDW + ((128 + dof + i * 8) ^ msw)];
    bf16x8 k3 = *(const bf16x8*)&ksh[m * LDW + ((192 + dof + i * 8) ^ msw)];
    #pragma unroll
    for (int j = 0; j < 8; ++j) {
      float qf = (float)qv[j];
      d0 += qf * (float)k0[j];
      d1 += qf * (float)k1[j];
      d2 += qf * (float)k2[j];
      d3 += qf * (float)k3[j];
    }
  }
  d0 += __shfl_xor(d0, 4);  d0 += __shfl_xor(d0, 8);
  d1 += __shfl_xor(d1, 4);  d1 += __shfl_xor(d1, 8);
  d2 += __shfl_xor(d2, 4);  d2 += __shfl_xor(d2, 8);
  d3 += __shfl_xor(d3, 4);  d3 += __shfl_xor(d3, 8);
  d0 *= 0.125f; d1 *= 0.125f; d2 *= 0.125f; d3 *= 0.125f;
  float mx = fmaxf(fmaxf(d0, d1), fmaxf(d2, d3));
  float e0 = expf(d0 - mx), e1 = expf(d1 - mx), e2 = expf(d2 - mx), e3 = expf(d3 - mx);
  float inv = 1.0f / (e0 + e1 + e2 + e3);
  float pg0 = e0 * inv, pg1 = e1 * inv, pg2 = e2 * inv, pg3 = e3 * inv;

  const int src = (lane & 48) | (sub >> 2);
  float p0 = __shfl(pg0, src);
  float p1 = __shfl(pg1, src);
  float p2 = __shfl(pg2, src);
  float p3 = __shfl(pg3, src);

  const int hy = sub >> 2;
  const int c0 = (sub & 3) * 16;
  #pragma unroll
  for (int i = 0; i < 2; ++i) {
    int c = c0 + i * 8;
    bf16x8 v0 = *(const bf16x8*)&vs[m * LDW + ((  0 + c) ^ msw)];
    bf16x8 v1 = *(const bf16x8*)&vs[m * LDW + (( 64 + c) ^ msw)];
    bf16x8 v2 = *(const bf16x8*)&vs[m * LDW + ((128 + c) ^ msw)];
    bf16x8 v3 = *(const bf16x8*)&vs[m * LDW + ((192 + c) ^ msw)];
    bf16x8 yv;
    #pragma unroll
    for (int j = 0; j < 8; ++j) {
      float f = p0 * (float)v0[j] + p1 * (float)v1[j]
              + p2 * (float)v2[j] + p3 * (float)v3[j];
      yv[j] = (__bf16)f;
    }
    *(bf16x8*)&ys[m * LDW + ((hy * 64 + c) ^ msw)] = yv;
  }
}

// ---------- p1: staging only ----------
__launch_bounds__(512, 4)
__global__ void p1_stage(const float* __restrict__ x, int nrep) {
  __shared__ __bf16 lds[4 * MROWS * LDW];
  __bf16* xs = lds;
  const int tid = threadIdx.x;
  const int tok0 = blockIdx.x * MROWS;
  for (int r = 0; r < nrep; ++r) {
    stage_x(x, xs, tid, tok0, zreg());
    __syncthreads();
    float s = (float)xs[tid] + (float)lds[MROWS * LDW + tid];
    asm volatile("" :: "v"(s));
    __syncthreads();
  }
}

// ---------- p2: stage + QKV compute WITHOUT global W loads ----------
__launch_bounds__(512, 4)
__global__ void p2_qkv_noW(const float* __restrict__ x,
                           const float* __restrict__ bq, const float* __restrict__ bk,
                           const float* __restrict__ bv, int nrep) {
  __shared__ __bf16 lds[4 * MROWS * LDW];
  __bf16* xs = lds;
  __bf16* qs = lds + 1 * MROWS * LDW;
  __bf16* ksh = lds + 2 * MROWS * LDW;
  __bf16* vs = lds + 3 * MROWS * LDW;
  const int tid = threadIdx.x, lane = tid & 63, w = tid >> 6;
  const int lh = lane & 15, lq = lane >> 4, n0 = w * 32;
  const int tok0 = blockIdx.x * MROWS;
  for (int r = 0; r < nrep; ++r) {
    stage_x(x, xs, tid, tok0, zreg());
    __syncthreads();
    f32x4 aq[2][2], ak[2][2], av[2][2];
    ZERO_ACC22(aq);
    ZERO_ACC22(ak);
    ZERO_ACC22(av);
    // launder acc starts so the 3 identical MFMA chains can't be CSE'd
    aq[0][0][0] += zregf(); ak[0][0][0] += zregf(); av[0][0][0] += zregf();
    const int xsw = ((lh >> 3) & 1) << 4;
    const __bf16* ap = xs + lh * LDW;
    #pragma unroll
    for (int kk = 0; kk < 8; ++kk) {
      const int c = (kk * 32 + lq * 8) ^ xsw;
      bf16x8 a0 = *(const bf16x8*)(ap +  0 * LDW + c);
      bf16x8 a1 = *(const bf16x8*)(ap + 16 * LDW + c);
      MFMA(aq[0][0], a0, a0); MFMA(aq[1][0], a1, a0);
      MFMA(aq[0][1], a0, a1); MFMA(aq[1][1], a1, a1);
      MFMA(ak[0][0], a0, a0); MFMA(ak[1][0], a1, a0);
      MFMA(ak[0][1], a0, a1); MFMA(ak[1][1], a1, a1);
      MFMA(av[0][0], a0, a0); MFMA(av[1][0], a1, a0);
      MFMA(av[0][1], a0, a1); MFMA(av[1][1], a1, a1);
    }
    store_cd32(qs, aq, bq, n0, lh, lq);
    store_cd32(ksh, ak, bk, n0, lh, lq);
    store_cd32(vs, av, bv, n0, lh, lq);
    __syncthreads();
    float s = (float)qs[tid] + (float)ksh[tid] + (float)vs[tid];
    asm volatile("" :: "v"(s));
    __syncthreads();
  }
}

// ---------- p3: stage + real QKV (XCD-local W) ----------
__launch_bounds__(512, 4)
__global__ void p3_qkv(const float* __restrict__ x, const __bf16* __restrict__ Wpk,
                       const float* __restrict__ bq, const float* __restrict__ bk,
                       const float* __restrict__ bv, int nrep) {
  __shared__ __bf16 lds[4 * MROWS * LDW];
  __bf16* xs = lds;
  __bf16* qs = lds + 1 * MROWS * LDW;
  __bf16* ksh = lds + 2 * MROWS * LDW;
  __bf16* vs = lds + 3 * MROWS * LDW;
  const int tid = threadIdx.x, lane = tid & 63, w = tid >> 6;
  const int lh = lane & 15, lq = lane >> 4, n0 = w * 32;
  const int tok0 = blockIdx.x * MROWS;
  const size_t cbase = (size_t)(blockIdx.x & 7) * CELEM;
  for (int r = 0; r < nrep; ++r) {
    stage_x(x, xs, tid, tok0, zreg());
    __syncthreads();
    const __bf16* base = Wpk + cbase + zreg();
    const __bf16* wlq = base + (size_t)(0 * 128 + w * 16) * 512 + lane * 8;
    const __bf16* wlk = base + (size_t)(1 * 128 + w * 16) * 512 + lane * 8;
    const __bf16* wlv = base + (size_t)(2 * 128 + w * 16) * 512 + lane * 8;
    qkv_pass(xs, qs, ksh, vs, wlq, wlk, wlv, bq, bk, bv, n0, lh, lq);
    __syncthreads();
    float s = (float)qs[tid] + (float)ksh[tid] + (float)vs[tid];
    asm volatile("" :: "v"(s));
    __syncthreads();
  }
}

// ---------- p4: stage + QKV + softmax/ymix ----------
__launch_bounds__(512, 4)
__global__ void p4_qkvsm(const float* __restrict__ x, const __bf16* __restrict__ Wpk,
                         const float* __restrict__ bq, const float* __restrict__ bk,
                         const float* __restrict__ bv, int nrep) {
  __shared__ __bf16 lds[4 * MROWS * LDW];
  __bf16* xs = lds;
  __bf16* qs = lds + 1 * MROWS * LDW;
  __bf16* ksh = lds + 2 * MROWS * LDW;
  __bf16* vs = lds + 3 * MROWS * LDW;
  const int tid = threadIdx.x, lane = tid & 63, w = tid >> 6;
  const int lh = lane & 15, lq = lane >> 4, n0 = w * 32;
  const int tok0 = blockIdx.x * MROWS;
  const size_t cbase = (size_t)(blockIdx.x & 7) * CELEM;
  for (int r = 0; r < nrep; ++r) {
    stage_x(x, xs, tid, tok0, zreg());
    __syncthreads();
    const __bf16* base = Wpk + cbase + zreg();
    const __bf16* wlq = base + (size_t)(0 * 128 + w * 16) * 512 + lane * 8;
    const __bf16* wlk = base + (size_t)(1 * 128 + w * 16) * 512 + lane * 8;
    const __bf16* wlv = base + (size_t)(2 * 128 + w * 16) * 512 + lane * 8;
    qkv_pass(xs, qs, ksh, vs, wlq, wlk, wlv, bq, bk, bv, n0, lh, lq);
    __syncthreads();
    sm_ymix(qs, ksh, vs, xs, tid);
    __syncthreads();
    float s = (float)xs[tid];
    asm volatile("" :: "v"(s));
    __syncthreads();
  }
}

// ---------- real kernel: R15-measured form, unchanged ----------
__launch_bounds__(512, 4)
__global__ void fused_attn(const float* __restrict__ x, const __bf16* __restrict__ Wpk,
                           const float* __restrict__ bq, const float* __restrict__ bk,
                           const float* __restrict__ bv, const float* __restrict__ bo,
                           float* __restrict__ out) {
  __shared__ __bf16 lds[4 * MROWS * LDW];
  __bf16* xs  = lds;
  __bf16* qs  = lds + 1 * MROWS * LDW;
  __bf16* ksh = lds + 2 * MROWS * LDW;
  __bf16* vs  = lds + 3 * MROWS * LDW;
  float*  ostage = (float*)(lds + 1 * MROWS * LDW);

  const int tid = threadIdx.x, lane = tid & 63, w = tid >> 6;
  const int lh = lane & 15, lq = lane >> 4, n0 = w * 32;
  const int tok0 = blockIdx.x * MROWS;

  stage_x(x, xs, tid, tok0, 0);

  const __bf16* base = Wpk + (size_t)(blockIdx.x & 7) * CELEM;
  const __bf16* wlq = base + (size_t)(0 * 128 + w * 16) * 512 + lane * 8;
  const __bf16* wlk = base + (size_t)(1 * 128 + w * 16) * 512 + lane * 8;
  const __bf16* wlv = base + (size_t)(2 * 128 + w * 16) * 512 + lane * 8;
  const __bf16* wlo = base + (size_t)(3 * 128 + w * 16) * 512 + lane * 8;

  __syncthreads();
  qkv_pass(xs, qs, ksh, vs, wlq, wlk, wlv, bq, bk, bv, n0, lh, lq);
  __syncthreads();
  sm_ymix(qs, ksh, vs, xs, tid);
  __syncthreads();

  {
    f32x4 acc[2][2];
    ZERO_ACC22(acc);
    const int xsw = ((lh >> 3) & 1) << 4;
    const __bf16* ap = xs + lh * LDW;
    #pragma unroll
    for (int kk = 0; kk < 8; ++kk) {
      bf16x8 w0 = *(const bf16x8*)(wlo + (0 * 8 + kk) * 512);
      bf16x8 w1 = *(const bf16x8*)(wlo + (1 * 8 + kk) * 512);
      const int c = (kk * 32 + lq * 8) ^ xsw;
      bf16x8 a0 = *(const bf16x8*)(ap +  0 * LDW + c);
      bf16x8 a1 = *(const bf16x8*)(ap + 16 * LDW + c);
      MFMA(acc[0][0], a0, w0); MFMA(acc[1][0], a1, w0);
      MFMA(acc[0][1], a0, w1); MFMA(acc[1][1], a1, w1);
    }
    #pragma unroll
    for (int nf = 0; nf < 2; ++nf) {
      int col = n0 + nf * 16 + lh;
      float bb = bo[col];
      #pragma unroll
      for (int mf = 0; mf < 2; ++mf) {
        int r = mf * 16 + lq * 4;
        #pragma unroll
        for (int j = 0; j < 4; ++j)
          ostage[(r + j) * OSTR + col] = acc[mf][nf][j] + bb;
      }
    }
    __syncthreads();
    float4* og = (float4*)(out + (size_t)tok0 * 256);
    #pragma unroll
    for (int i = 0; i < 4; ++i) {
      int idx = i * 512 + tid;
      int row = idx >> 6;
      int c4  = idx & 63;
      float4 v = *(const float4*)&ostage[row * OSTR + c4 * 4];
      og[(size_t)row * 64 + c4] = v;
    }
  }
}

extern "C" void kernel_launch(void* const* d_in, const int* in_sizes, int n_in,
                              void* d_out, int out_size, void* d_ws, size_t ws_size,
                              hipStream_t stream) {
  const float* x  = (const float*)d_in[0];
  const float* Wq = (const float*)d_in[1];
  const float* bq = (const float*)d_in[2];
  const float* Wk = (const float*)d_in[3];
  const float* bk = (const float*)d_in[4];
  const float* Wv = (const float*)d_in[5];
  const float* bv = (const float*)d_in[6];
  const float* Wo = (const float*)d_in[7];
  const float* bo = (const float*)d_in[8];
  float* out = (float*)d_out;
  __bf16* Wpk = (__bf16*)d_ws;   // 8 copies x 512 KB = 4 MB

  pack_wfrag8<<<dim3(4096), dim3(64), 0, stream>>>(Wq, Wk, Wv, Wo, Wpk);
  fused_attn<<<dim3(1024), dim3(512), 0, stream>>>(x, Wpk, bq, bk, bv, bo, out);
  p1_stage <<<dim3(1024), dim3(512), 0, stream>>>(x, 20);
  p2_qkv_noW<<<dim3(1024), dim3(512), 0, stream>>>(x, bq, bk, bv, 8);
  p3_qkv   <<<dim3(1024), dim3(512), 0, stream>>>(x, Wpk, bq, bk, bv, 6);
  p4_qkvsm <<<dim3(1024), dim3(512), 0, stream>>>(x, Wpk, bq, bk, bv, 4);
}

// Round 17
// 327.889 us; speedup vs baseline: 1.1948x; 1.1948x over previous
//
#include <hip/hip_runtime.h>

// B=8, S=4096, E=256, H=4, DK=64. Tokens = B*S = 32768.
// Round-17: CLOCK PROBE. R16's p3 number (stage+QKV = 10.2us/block = 24.4K
// cyc @2.4GHz nominal) is ~10x its instruction content. Cross-check of
// MfmaUtil vs hand-counted MFMA cycles implies shader clock ~340 MHz during
// both p3 (27% util) and fused (14.5% util) - consistent across kernels.
// Theory #8: GFX-domain DVFS floor (fills/rocprof gaps are GFX-idle) makes
// wall time ~= cycles/f_low, explaining why SEVEN structural changes were
// all neutral at 42-44us.
// Probe: dependent-FMA chain of known length (50K fmas x 4cyc = ~210K cyc,
// incl. loop overhead), 256 blocks x 64 thr (1 wave/CU, latency-bound,
// contention-free), launched where fused normally runs. Its dur gives
// clock = 210K/dur. >=83us even at 2.4GHz -> guaranteed top-5 visibility.
// fused kept in R15-measured form (coalesced epilogue) for continuity.

typedef __bf16 bf16x8 __attribute__((ext_vector_type(8)));
typedef __bf16 bf16x4 __attribute__((ext_vector_type(4)));
typedef float f32x4 __attribute__((ext_vector_type(4)));

#define LDW 264
#define MROWS 32
#define XSW(row, col) ((col) ^ ((((row) >> 3) & 1) << 4))
#define CELEM (512 * 512)
#define OSTR 260

__global__ void pack_wfrag8(const float* __restrict__ Wq, const float* __restrict__ Wk,
                            const float* __restrict__ Wv, const float* __restrict__ Wo,
                            __bf16* __restrict__ Wpk) {
  const int c = blockIdx.x & 7;
  const int f = blockIdx.x >> 3;
  const int lane = threadIdx.x;
  const int kk = f & 7, g16 = (f >> 3) & 15, p = f >> 7;
  const float* W = (p == 0) ? Wq : (p == 1) ? Wk : (p == 2) ? Wv : Wo;
  const int lh = lane & 15, lq = lane >> 4;
  const int n = g16 * 16 + lh, k0 = kk * 32 + lq * 8;
  const float4 s0 = *(const float4*)&W[n * 256 + k0];
  const float4 s1 = *(const float4*)&W[n * 256 + k0 + 4];
  bf16x8 r;
  r[0] = (__bf16)s0.x; r[1] = (__bf16)s0.y; r[2] = (__bf16)s0.z; r[3] = (__bf16)s0.w;
  r[4] = (__bf16)s1.x; r[5] = (__bf16)s1.y; r[6] = (__bf16)s1.z; r[7] = (__bf16)s1.w;
  *(bf16x8*)&Wpk[(size_t)c * CELEM + (size_t)f * 512 + lane * 8] = r;
}

// ---------- clock probe: dependent FMA chain of known cycle length ----------
// 6250 outer iters x 8 dependent fmaf = 50,000 fmas x 4 cyc (dep latency,
// m07) ~= 200K cyc + ~10K loop overhead. dur_us -> clock = ~210e3/dur MHz.
__global__ void clk_probe(float* __restrict__ sink, int nouter) {
  float a = 1.0f + (float)threadIdx.x * 1e-7f;
  for (int i = 0; i < nouter; ++i) {
    #pragma unroll
    for (int j = 0; j < 8; ++j)
      a = __builtin_fmaf(a, 0.9999999f, 1e-9f);
  }
  if (a == 12345.0f) sink[blockIdx.x] = a;   // never true; keeps chain live
}

#define MFMA(d, a, b) d = __builtin_amdgcn_mfma_f32_16x16x32_bf16(a, b, d, 0, 0, 0)

#define ZERO_ACC22(acc)                                          \
  _Pragma("unroll")                                              \
  for (int mf_ = 0; mf_ < 2; ++mf_)                              \
    _Pragma("unroll")                                            \
    for (int nf_ = 0; nf_ < 2; ++nf_)                            \
      acc[mf_][nf_] = (f32x4){0.f, 0.f, 0.f, 0.f};

__device__ __forceinline__ void store_cd32(__bf16* __restrict__ buf, const f32x4 acc[2][2],
                                           const float* __restrict__ bias,
                                           int n0, int lh, int lq) {
  #pragma unroll
  for (int nf = 0; nf < 2; ++nf) {
    int col = n0 + nf * 16 + lh;
    float bb = bias[col];
    #pragma unroll
    for (int mf = 0; mf < 2; ++mf) {
      int r = mf * 16 + lq * 4;
      #pragma unroll
      for (int j = 0; j < 4; ++j)
        buf[(r + j) * LDW + XSW(r + j, col)] = (__bf16)(acc[mf][nf][j] + bb);
    }
  }
}

__launch_bounds__(512, 4)
__global__ void fused_attn(const float* __restrict__ x, const __bf16* __restrict__ Wpk,
                           const float* __restrict__ bq, const float* __restrict__ bk,
                           const float* __restrict__ bv, const float* __restrict__ bo,
                           float* __restrict__ out) {
  __shared__ __bf16 lds[4 * MROWS * LDW];
  __bf16* xs  = lds;
  __bf16* qs  = lds + 1 * MROWS * LDW;
  __bf16* ksh = lds + 2 * MROWS * LDW;
  __bf16* vs  = lds + 3 * MROWS * LDW;
  float*  ostage = (float*)(lds + 1 * MROWS * LDW);

  const int tid = threadIdx.x, lane = tid & 63, w = tid >> 6;
  const int lh = lane & 15, lq = lane >> 4, n0 = w * 32;
  const int tok0 = blockIdx.x * MROWS;

  const float4* xg = (const float4*)(x + (size_t)tok0 * 256);
  #pragma unroll
  for (int i = 0; i < 4; ++i) {
    int idx = i * 512 + tid;
    int row = idx >> 6;
    int c4  = idx & 63;
    float4 v = xg[idx];
    bf16x4 pk;
    pk[0] = (__bf16)v.x; pk[1] = (__bf16)v.y; pk[2] = (__bf16)v.z; pk[3] = (__bf16)v.w;
    *(bf16x4*)&xs[row * LDW + XSW(row, c4 * 4)] = pk;
  }

  const __bf16* base = Wpk + (size_t)(blockIdx.x & 7) * CELEM;
  const __bf16* wlq = base + (size_t)(0 * 128 + w * 16) * 512 + lane * 8;
  const __bf16* wlk = base + (size_t)(1 * 128 + w * 16) * 512 + lane * 8;
  const __bf16* wlv = base + (size_t)(2 * 128 + w * 16) * 512 + lane * 8;
  const __bf16* wlo = base + (size_t)(3 * 128 + w * 16) * 512 + lane * 8;

  __syncthreads();

  {
    f32x4 aq[2][2], ak[2][2], av[2][2];
    ZERO_ACC22(aq);
    ZERO_ACC22(ak);
    ZERO_ACC22(av);
    const int xsw = ((lh >> 3) & 1) << 4;
    const __bf16* ap = xs + lh * LDW;
    #pragma unroll
    for (int kk = 0; kk < 8; ++kk) {
      bf16x8 wq0 = *(const bf16x8*)(wlq + (0 * 8 + kk) * 512);
      bf16x8 wq1 = *(const bf16x8*)(wlq + (1 * 8 + kk) * 512);
      bf16x8 wk0 = *(const bf16x8*)(wlk + (0 * 8 + kk) * 512);
      bf16x8 wk1 = *(const bf16x8*)(wlk + (1 * 8 + kk) * 512);
      bf16x8 wv0 = *(const bf16x8*)(wlv + (0 * 8 + kk) * 512);
      bf16x8 wv1 = *(const bf16x8*)(wlv + (1 * 8 + kk) * 512);
      const int c = (kk * 32 + lq * 8) ^ xsw;
      bf16x8 a0 = *(const bf16x8*)(ap +  0 * LDW + c);
      bf16x8 a1 = *(const bf16x8*)(ap + 16 * LDW + c);
      MFMA(aq[0][0], a0, wq0); MFMA(aq[1][0], a1, wq0);
      MFMA(aq[0][1], a0, wq1); MFMA(aq[1][1], a1, wq1);
      MFMA(ak[0][0], a0, wk0); MFMA(ak[1][0], a1, wk0);
      MFMA(ak[0][1], a0, wk1); MFMA(ak[1][1], a1, wk1);
      MFMA(av[0][0], a0, wv0); MFMA(av[1][0], a1, wv0);
      MFMA(av[0][1], a0, wv1); MFMA(av[1][1], a1, wv1);
    }
    store_cd32(qs, aq, bq, n0, lh, lq);
    store_cd32(ksh, ak, bk, n0, lh, lq);
    store_cd32(vs, av, bv, n0, lh, lq);
  }
  __syncthreads();

  {
    const int m   = tid >> 4;
    const int sub = tid & 15;
    const int h   = sub & 3;
    const int kh  = sub >> 2;
    const int dof = kh * 16;
    const int msw = ((m >> 3) & 1) << 4;
    float d0 = 0.f, d1 = 0.f, d2 = 0.f, d3 = 0.f;
    #pragma unroll
    for (int i = 0; i < 2; ++i) {
      bf16x8 qv = *(const bf16x8*)&qs[m * LDW + ((h * 64 + dof + i * 8) ^ msw)];
      bf16x8 k0 = *(const bf16x8*)&ksh[m * LDW + ((  0 + dof + i * 8) ^ msw)];
      bf16x8 k1 = *(const bf16x8*)&ksh[m * LDW + (( 64 + dof + i * 8) ^ msw)];
      bf16x8 k2 = *(const bf16x8*)&ksh[m * LDW + ((128 + dof + i * 8) ^ msw)];
      bf16x8 k3 = *(const bf16x8*)&ksh[m * LDW + ((192 + dof + i * 8) ^ msw)];
      #pragma unroll
      for (int j = 0; j < 8; ++j) {
        float qf = (float)qv[j];
        d0 += qf * (float)k0[j];
        d1 += qf * (float)k1[j];
        d2 += qf * (float)k2[j];
        d3 += qf * (float)k3[j];
      }
    }
    d0 += __shfl_xor(d0, 4);  d0 += __shfl_xor(d0, 8);
    d1 += __shfl_xor(d1, 4);  d1 += __shfl_xor(d1, 8);
    d2 += __shfl_xor(d2, 4);  d2 += __shfl_xor(d2, 8);
    d3 += __shfl_xor(d3, 4);  d3 += __shfl_xor(d3, 8);
    d0 *= 0.125f; d1 *= 0.125f; d2 *= 0.125f; d3 *= 0.125f;
    float mx = fmaxf(fmaxf(d0, d1), fmaxf(d2, d3));
    float e0 = expf(d0 - mx), e1 = expf(d1 - mx), e2 = expf(d2 - mx), e3 = expf(d3 - mx);
    float inv = 1.0f / (e0 + e1 + e2 + e3);
    float pg0 = e0 * inv, pg1 = e1 * inv, pg2 = e2 * inv, pg3 = e3 * inv;

    const int src = (lane & 48) | (sub >> 2);
    float p0 = __shfl(pg0, src);
    float p1 = __shfl(pg1, src);
    float p2 = __shfl(pg2, src);
    float p3 = __shfl(pg3, src);

    const int hy = sub >> 2;
    const int c0 = (sub & 3) * 16;
    #pragma unroll
    for (int i = 0; i < 2; ++i) {
      int c = c0 + i * 8;
      bf16x8 v0 = *(const bf16x8*)&vs[m * LDW + ((  0 + c) ^ msw)];
      bf16x8 v1 = *(const bf16x8*)&vs[m * LDW + (( 64 + c) ^ msw)];
      bf16x8 v2 = *(const bf16x8*)&vs[m * LDW + ((128 + c) ^ msw)];
      bf16x8 v3 = *(const bf16x8*)&vs[m * LDW + ((192 + c) ^ msw)];
      bf16x8 yv;
      #pragma unroll
      for (int j = 0; j < 8; ++j) {
        float f = p0 * (float)v0[j] + p1 * (float)v1[j]
                + p2 * (float)v2[j] + p3 * (float)v3[j];
        yv[j] = (__bf16)f;
      }
      *(bf16x8*)&xs[m * LDW + ((hy * 64 + c) ^ msw)] = yv;
    }
  }
  __syncthreads();

  {
    f32x4 acc[2][2];
    ZERO_ACC22(acc);
    const int xsw = ((lh >> 3) & 1) << 4;
    const __bf16* ap = xs + lh * LDW;
    #pragma unroll
    for (int kk = 0; kk < 8; ++kk) {
      bf16x8 w0 = *(const bf16x8*)(wlo + (0 * 8 + kk) * 512);
      bf16x8 w1 = *(const bf16x8*)(wlo + (1 * 8 + kk) * 512);
      const int c = (kk * 32 + lq * 8) ^ xsw;
      bf16x8 a0 = *(const bf16x8*)(ap +  0 * LDW + c);
      bf16x8 a1 = *(const bf16x8*)(ap + 16 * LDW + c);
      MFMA(acc[0][0], a0, w0); MFMA(acc[1][0], a1, w0);
      MFMA(acc[0][1], a0, w1); MFMA(acc[1][1], a1, w1);
    }
    #pragma unroll
    for (int nf = 0; nf < 2; ++nf) {
      int col = n0 + nf * 16 + lh;
      float bb = bo[col];
      #pragma unroll
      for (int mf = 0; mf < 2; ++mf) {
        int r = mf * 16 + lq * 4;
        #pragma unroll
        for (int j = 0; j < 4; ++j)
          ostage[(r + j) * OSTR + col] = acc[mf][nf][j] + bb;
      }
    }
    __syncthreads();
    float4* og = (float4*)(out + (size_t)tok0 * 256);
    #pragma unroll
    for (int i = 0; i < 4; ++i) {
      int idx = i * 512 + tid;
      int row = idx >> 6;
      int c4  = idx & 63;
      float4 v = *(const float4*)&ostage[row * OSTR + c4 * 4];
      og[(size_t)row * 64 + c4] = v;
    }
  }
}

extern "C" void kernel_launch(void* const* d_in, const int* in_sizes, int n_in,
                              void* d_out, int out_size, void* d_ws, size_t ws_size,
                              hipStream_t stream) {
  const float* x  = (const float*)d_in[0];
  const float* Wq = (const float*)d_in[1];
  const float* bq = (const float*)d_in[2];
  const float* Wk = (const float*)d_in[3];
  const float* bk = (const float*)d_in[4];
  const float* Wv = (const float*)d_in[5];
  const float* bv = (const float*)d_in[6];
  const float* Wo = (const float*)d_in[7];
  const float* bo = (const float*)d_in[8];
  float* out = (float*)d_out;
  __bf16* Wpk = (__bf16*)d_ws;                       // 8 copies x 512 KB = 4 MB
  float* sink = (float*)((char*)d_ws + (8u << 20));  // never actually written

  pack_wfrag8<<<dim3(4096), dim3(64), 0, stream>>>(Wq, Wk, Wv, Wo, Wpk);
  clk_probe  <<<dim3(256),  dim3(64), 0, stream>>>(sink, 6250);   // ~210K cyc chain
  fused_attn <<<dim3(1024), dim3(512), 0, stream>>>(x, Wpk, bq, bk, bv, bo, out);
}